// Round 6
// baseline (166.487 us; speedup 1.0000x reference)
//
#include <hip/hip_runtime.h>
#include <hip/hip_bf16.h>

// TypedLinear: y[i] = W[types[i]] @ x[i] + b[types[i]]
// B=131072, T=8, IN=OUT=128, fp32 in/out.
// v3: occupancy attack. v2 (128-tok/256-thr) was latency-bound at 52us:
// 16 waves/CU (29% occ), VGPR=52 proved staging loads got serialized, no pipe
// >10%. v3 = 64-token blocks x 512 threads (8 waves x 16 output cols each),
// VGPR target <=64 -> 32 waves/CU. Swizzled LDS x-tile + bucketed MFMA
// structure carried over from v2 (verified absmax 0.03125).

typedef __attribute__((ext_vector_type(8))) short bf16x8;   // 8 bf16 (one ds_read_b128)
typedef __attribute__((ext_vector_type(4))) short short4v;  // 4 bf16 (one ds_write_b64)
typedef __attribute__((ext_vector_type(4))) float f32x4;    // MFMA accumulator
typedef __attribute__((ext_vector_type(4))) float float4v;

static constexpr int kBT      = 64;    // tokens per block
static constexpr int kT       = 8;     // number of types
static constexpr int kD       = 128;   // IN = OUT = 128
static constexpr int kThreads = 512;   // 8 waves

__device__ __forceinline__ short f2bf(float f) {
  union { __hip_bfloat16 h; short u; } cv;
  cv.h = __float2bfloat16(f);
  return cv.u;
}

// Prep: convert W (8*128*128 fp32) -> bf16 in workspace (256 KiB, L2-resident).
__global__ __launch_bounds__(256) void wconv_kernel(const float* __restrict__ W,
                                                    short* __restrict__ Wb) {
  const int i = (blockIdx.x * 256 + threadIdx.x) * 8;
  float4v a = *(const float4v*)(W + i);
  float4v b = *(const float4v*)(W + i + 4);
  bf16x8 r;
  r[0] = f2bf(a[0]); r[1] = f2bf(a[1]); r[2] = f2bf(a[2]); r[3] = f2bf(a[3]);
  r[4] = f2bf(b[0]); r[5] = f2bf(b[1]); r[6] = f2bf(b[2]); r[7] = f2bf(b[3]);
  *(bf16x8*)(Wb + i) = r;
}

// 512 threads = 8 waves; block = 64 consecutive tokens. Wave w owns output
// cols [w*16, w*16+16). Phases: coalesced reg-stage x (4 float4/thread) ->
// bucket-by-type -> cvt+swizzled LDS write -> per-type {W frags from L2,
// A frags gathered from LDS, 4x mfma_16x16x32_bf16, masked scattered stores}.
__global__ __launch_bounds__(kThreads, 8) void typed_linear_kernel(
    const float* __restrict__ x, const int* __restrict__ types,
    const short* __restrict__ Wb, const float* __restrict__ bias,
    float* __restrict__ y) {
  __shared__ short xb[kBT * kD];            // 16 KiB swizzled bf16 x-tile
  __shared__ int s_cnt[kT];
  __shared__ unsigned char s_list[kT][kBT];

  const int tid  = threadIdx.x;
  const int tok0 = blockIdx.x * kBT;

  // --- stage: 4 coalesced float4 loads/thread (issued back-to-back)
  const float* xg = x + (size_t)tok0 * kD;
  float4v xr[4];
#pragma unroll
  for (int i = 0; i < 4; ++i)
    xr[i] = *(const float4v*)(xg + i * (kThreads * 4) + tid * 4);

  // --- bucket by type (overlaps load latency)
  if (tid < kT) s_cnt[tid] = 0;
  __syncthreads();
  if (tid < kBT) {
    const int t = types[tok0 + tid];
    const int pos = atomicAdd(&s_cnt[t], 1);
    s_list[t][pos] = (unsigned char)tid;
  }

  // --- cvt + swizzled LDS write (16B slot ^= row&7; write is 8B half-slot)
#pragma unroll
  for (int i = 0; i < 4; ++i) {
    const int f    = i * (kThreads * 4) + tid * 4;  // flat float idx in 64x128
    const int row  = f >> 7;
    const int col  = f & 127;                       // col%8 in {0,4}
    const int slot = (col >> 3) ^ (row & 7);
    short4v v;
    v[0] = f2bf(xr[i][0]); v[1] = f2bf(xr[i][1]);
    v[2] = f2bf(xr[i][2]); v[3] = f2bf(xr[i][3]);
    *(short4v*)(xb + row * kD + slot * 8 + (col & 7)) = v;
  }
  __syncthreads();

  const int w    = tid >> 6;    // wave 0..7 -> output cols [w*16, w*16+16)
  const int lane = tid & 63;
  const int lr   = lane & 15;   // A-row / B-col / C-col key
  const int lg   = lane >> 4;   // k-group 0..3

  const short* wbase = Wb + (w * 16 + lr) * kD;

#pragma unroll
  for (int t = 0; t < kT; ++t) {
    const int cnt = s_cnt[t];

    // B fragments: B[k][o] = W[t][o][k]; same assumed k-map as A (any shared
    // k-bijection is correct).
    bf16x8 bfr[4];
    const short* wrow = wbase + t * kD * kD;
#pragma unroll
    for (int s = 0; s < 4; ++s)
      bfr[s] = *(const bf16x8*)(wrow + s * 32 + lg * 8);
    const float bias0 = bias[t * kD + w * 16 + lr];

    for (int m0 = 0; m0 < cnt; m0 += 16) {
      int ia = m0 + lr;
      ia = ia < cnt ? ia : cnt - 1;         // clamped dup for ragged tail
      const int row = s_list[t][ia];

      // A fragments from swizzled LDS: slot = (s*4+lg) ^ (row&7)
      bf16x8 afr[4];
#pragma unroll
      for (int s = 0; s < 4; ++s) {
        const int slot = ((s << 2) + lg) ^ (row & 7);
        afr[s] = *(const bf16x8*)(xb + row * kD + slot * 8);
      }

      f32x4 acc = {0.f, 0.f, 0.f, 0.f};
#pragma unroll
      for (int s = 0; s < 4; ++s)
        acc = __builtin_amdgcn_mfma_f32_16x16x32_bf16(afr[s], bfr[s], acc, 0, 0, 0);

      // C/D layout (HW-verified): col = lane&15, row = (lane>>4)*4 + reg
#pragma unroll
      for (int r = 0; r < 4; ++r) {
        const int rl = lg * 4 + r;
        if (m0 + rl < cnt) {
          y[(size_t)(tok0 + s_list[t][m0 + rl]) * kD + w * 16 + lr] = acc[r] + bias0;
        }
      }
    }
  }
}

extern "C" void kernel_launch(void* const* d_in, const int* in_sizes, int n_in,
                              void* d_out, int out_size, void* d_ws, size_t ws_size,
                              hipStream_t stream) {
  const float* x     = (const float*)d_in[0];
  const int*   types = (const int*)d_in[1];
  const float* W     = (const float*)d_in[2];
  const float* bias  = (const float*)d_in[3];
  float*       y     = (float*)d_out;
  short*       Wb    = (short*)d_ws;   // 8*128*128 bf16 = 256 KiB scratch

  const int n_tok = in_sizes[0] / kD;  // 131072

  wconv_kernel<<<(kT * kD * kD) / (256 * 8), 256, 0, stream>>>(W, Wb);
  typed_linear_kernel<<<n_tok / kBT, kThreads, 0, stream>>>(x, types, Wb, bias, y);
}